// Round 11
// baseline (96.675 us; speedup 1.0000x reference)
//
#include <hip/hip_runtime.h>
#include <hip/hip_bf16.h>
#include <math.h>

#define N_NODES 50000
#define N_EDGES 800000
#define F 64
#define CUTOFF2 100.0f

#define NPB 16                 // nodes per bucket; bucket = tgt >> 4
#define NBUCKET 3125           // 50000 / 16 exactly
#define CAP 160                // records/bucket (mean ~90, sigma ~9.5, +7 sigma)
#define NODE_BLOCKS 782        // ceil(3125 node-tiles / 4 waves)
#define PREP_BLOCKS 3125       // 800000 / 256 exactly
#define MAIN_BLOCKS 782        // ceil(3125 buckets / 4 waves-per-block)

typedef __attribute__((ext_vector_type(8))) short bf16x8;   // 8 bf16 = 4 VGPR
typedef __attribute__((ext_vector_type(4))) short bf16x4;   // 4 bf16 = 2 VGPR
typedef __attribute__((ext_vector_type(4))) float f32x4;    // MFMA C/D

// Division-free silu (R10, verified): v * rcp(1 + exp(-v)).
__device__ __forceinline__ float silu_f(float v) {
    return v * __builtin_amdgcn_rcpf(1.0f + __expf(-v));
}

// f32 -> bf16 bits, round-to-nearest-even
__device__ __forceinline__ unsigned short bf16_rne(float f) {
    unsigned int u = __float_as_uint(f);
    unsigned int r = (u + 0x7FFFu + ((u >> 16) & 1u)) >> 16;
    return (unsigned short)r;
}
__device__ __forceinline__ float bf16_f32(unsigned short h) {
    return __uint_as_float(((unsigned int)h) << 16);
}

// K=16 bf16 MFMA (legacy shape, gfx950 per cdna4_isa.md §10).
// Layouts (canonical CDNA 16x16x16):
//   A: row = lane&15, k = (lane>>4)*4 + j
//   B: col = lane&15, k = (lane>>4)*4 + j
//   D: col = lane&15, row = (lane>>4)*4 + reg
// Note B's k-position == the 16x16x32 D-row position -> the second GEMM's
// D output feeds this B operand with NO cross-lane movement.
__device__ __forceinline__ f32x4 mfma16k(bf16x4 a, bf16x4 b, f32x4 c) {
#if __has_builtin(__builtin_amdgcn_mfma_f32_16x16x16bf16_1k)
    return __builtin_amdgcn_mfma_f32_16x16x16bf16_1k(a, b, c, 0, 0, 0);
#elif __has_builtin(__builtin_amdgcn_mfma_f32_16x16x16_bf16)
    return __builtin_amdgcn_mfma_f32_16x16x16_bf16(a, b, c, 0, 0, 0);
#else
    f32x4 d = c;
    asm volatile("v_mfma_f32_16x16x16_bf16 %0, %1, %2, %0"
                 : "+v"(d) : "v"(a), "v"(b));
    return d;
#endif
}

// ---------------------------------------------------------------------------
// 16-row GEMM tile vs 64x64 row-major W (3-term bf16 split ~ f32 accuracy).
// MFMA f32_16x16x32_bf16 layouts (refcheck-verified rounds 3-10):
//   A: row = lane&15, k = (lane>>4)*8 + j
//   B: col = lane&15, k = (lane>>4)*8 + j
//   D: col = lane&15, row = (lane>>4)*4 + reg
// ---------------------------------------------------------------------------
__device__ __forceinline__ void gemm16_store(
    const bf16x8 (&Ah)[2], const bf16x8 (&Al)[2],
    const float* __restrict__ W, const float* __restrict__ bias,
    float* __restrict__ dst, int n0, int r, int g)
{
    #pragma unroll
    for (int c = 0; c < 4; ++c) {
        f32x4 acc = {0.f, 0.f, 0.f, 0.f};
        #pragma unroll
        for (int t = 0; t < 2; ++t) {
            bf16x8 bh, bl;
            #pragma unroll
            for (int j = 0; j < 8; ++j) {
                const float wv = W[(size_t)(t * 32 + g * 8 + j) * F + c * 16 + r];
                const unsigned short hb = bf16_rne(wv);
                bh[j] = (short)hb;
                bl[j] = (short)bf16_rne(wv - bf16_f32(hb));
            }
            acc = __builtin_amdgcn_mfma_f32_16x16x32_bf16(Ah[t], bh, acc, 0, 0, 0);
            acc = __builtin_amdgcn_mfma_f32_16x16x32_bf16(Al[t], bh, acc, 0, 0, 0);
            acc = __builtin_amdgcn_mfma_f32_16x16x32_bf16(Ah[t], bl, acc, 0, 0, 0);
        }
        const float bb = bias[c * 16 + r];
        #pragma unroll
        for (int rg = 0; rg < 4; ++rg) {
            dst[(size_t)(n0 + g * 4 + rg) * F + c * 16 + r] = acc[rg] + bb;
        }
    }
}

__global__ __launch_bounds__(256) void node_kernel(
    const float* __restrict__ x, const float* __restrict__ Wp,
    const float* __restrict__ bp, const float* __restrict__ W1,
    const float* __restrict__ b1, float* __restrict__ out,
    float* __restrict__ h1)
{
    const int lane = threadIdx.x & 63;
    const int gw   = blockIdx.x * 4 + (threadIdx.x >> 6);
    if (gw >= N_NODES / 16) return;
    const int n0 = gw * 16;
    const int r = lane & 15, g = lane >> 4;

    bf16x8 Ah[2], Al[2];
    #pragma unroll
    for (int t = 0; t < 2; ++t) {
        const float* xp = x + (size_t)(n0 + r) * F + t * 32 + g * 8;
        #pragma unroll
        for (int j = 0; j < 8; ++j) {
            const float v = xp[j];
            const unsigned short hb = bf16_rne(v);
            Ah[t][j] = (short)hb;
            Al[t][j] = (short)bf16_rne(v - bf16_f32(hb));
        }
    }
    gemm16_store(Ah, Al, Wp, bp, out, n0, r, g);
    gemm16_store(Ah, Al, W1, b1, h1, n0, r, g);
}

// ---------------------------------------------------------------------------
// Kernel 2: cutoff + radial MLP + bin-by-target-bucket (bucket = tgt>>4).
// One thread per edge. Record (32B): {src, tgt, r0..r3, cutoff, pad}.
// 280K atomicAdds spread over 3125 counters (~90 each) - distributed.
// ---------------------------------------------------------------------------
__global__ __launch_bounds__(256) void edge_prep_kernel(
    const int* __restrict__ ei, const float* __restrict__ pos,
    const float* __restrict__ Wr1, const float* __restrict__ br1,
    const float* __restrict__ Wr2, const float* __restrict__ br2,
    float* __restrict__ recs, int* __restrict__ counts)
{
    const int e = blockIdx.x * 256 + threadIdx.x;   // grid covers exactly
    const int src = ei[e];
    const int tgt = ei[N_EDGES + e];
    const float dx = pos[3 * tgt + 0] - pos[3 * src + 0];
    const float dy = pos[3 * tgt + 1] - pos[3 * src + 1];
    const float dz = pos[3 * tgt + 2] - pos[3 * src + 2];
    const float d2 = dx * dx + dy * dy + dz * dz;
    if (d2 >= CUTOFF2) return;

    const float d = sqrtf(d2);
    float a0 = br2[0], a1 = br2[1], a2 = br2[2], a3 = br2[3];
    #pragma unroll
    for (int i = 0; i < 16; ++i) {
        const float t = silu_f(fmaf(d, Wr1[i], br1[i]));
        a0 = fmaf(t, Wr2[i * 4 + 0], a0);
        a1 = fmaf(t, Wr2[i * 4 + 1], a1);
        a2 = fmaf(t, Wr2[i * 4 + 2], a2);
        a3 = fmaf(t, Wr2[i * 4 + 3], a3);
    }
    const float r0 = silu_f(a0), r1 = silu_f(a1);
    const float r2 = silu_f(a2), r3 = silu_f(a3);
    const float cut = 1.0f - d2 * 0.01f;    // in (0,1] when d2 < 100

    const int b   = tgt >> 4;               // NPB = 16
    const int idx = atomicAdd(&counts[b], 1);
    if (idx < CAP) {
        float4* p = (float4*)(recs + ((size_t)b * CAP + idx) * 8);
        p[0] = make_float4(__int_as_float(src), __int_as_float(tgt), r0, r1);
        p[1] = make_float4(r2, r3, cut, 0.0f);
    }
}

// ---------------------------------------------------------------------------
// Kernel 3 (R11): ZERO-ATOMIC edge MLP. One WAVE per 16-node bucket; the
// wave exclusively owns output rows [bkt*16, bkt*16+16).
// Per 16-edge tile (body identical to R10 through the 8 MFMAs), then:
//   aggr[16x64] += P^T[16x16] @ E[16x64]   via 8x mfma_16x16x16_bf16
// where P[row][edge] = (tgt==row) (exact 0/1) and E = silu(D2+b2)*cut,
// hi/lo bf16 2-term split (error ~1e-5). E needs NO lane movement: D2-row
// (lane>>4)*4+reg == B3-k (lane>>4)*4+j. acc3 accumulates in registers
// across all tiles; epilogue = 16 plain read-add-writes. No atomics, no
// LDS, no barriers anywhere in this kernel.
// Theory: R4/R5/R10 fit time ~ issue + RMW_bytes/(~512B/cy): the f32
// global atomics are memory-side RMWs (non-coherent per-XCD L2s) and
// rate-limit at ~40us. This removes them entirely.
// ---------------------------------------------------------------------------
__global__ __launch_bounds__(256, 3) void edge_main_kernel(
    const float* __restrict__ recs, const int* __restrict__ counts,
    const float* __restrict__ h1, const float* __restrict__ W1,
    const float* __restrict__ W2, const float* __restrict__ b2,
    float* __restrict__ out)
{
    const int lane = threadIdx.x & 63;
    const int w    = threadIdx.x >> 6;
    const int r    = lane & 15, g = lane >> 4;

    const int bkt = blockIdx.x * 4 + w;
    if (bkt >= NBUCKET) return;
    const int cnt = min(counts[bkt], CAP);
    if (cnt == 0) return;                 // wave-uniform; out rows keep node term

    // W2 B-fragments, bf16 single term (32 VGPRs). L2-hot across all waves.
    bf16x8 Bh[4][2];
    #pragma unroll
    for (int c = 0; c < 4; ++c)
        #pragma unroll
        for (int t = 0; t < 2; ++t)
            #pragma unroll
            for (int jj = 0; jj < 8; ++jj)
                Bh[c][t][jj] = (short)bf16_rne(
                    W2[(size_t)(t * 32 + g * 8 + jj) * F + c * 16 + r]);

    // W1 radial rows 64..67, this lane's k-slice (64 VGPRs, f32).
    float w1r[4][2][8];
    #pragma unroll
    for (int i = 0; i < 4; ++i)
        #pragma unroll
        for (int t = 0; t < 2; ++t) {
            const float4 wa = *(const float4*)&W1[(size_t)(F + i) * F + t * 32 + g * 8];
            const float4 wb = *(const float4*)&W1[(size_t)(F + i) * F + t * 32 + g * 8 + 4];
            w1r[i][t][0] = wa.x; w1r[i][t][1] = wa.y;
            w1r[i][t][2] = wa.z; w1r[i][t][3] = wa.w;
            w1r[i][t][4] = wb.x; w1r[i][t][5] = wb.y;
            w1r[i][t][6] = wb.z; w1r[i][t][7] = wb.w;
        }

    float b2c[4];
    #pragma unroll
    for (int c = 0; c < 4; ++c) b2c[c] = b2[c * 16 + r];

    const int node0 = bkt * NPB;
    const float* rbase = recs + (size_t)bkt * CAP * 8;
    const int ntiles = (cnt + 15) >> 4;

    f32x4 acc3[4] = {};   // output-stationary: aggr[4g+rg][c*16+r]

    for (int s = 0; s < ntiles; ++s) {
        const int base = s << 4;
        // Branch-free record load: all 64 lanes load edge (base + r).
        const int er = min(base + r, cnt - 1);
        const float4 ra = *(const float4*)(rbase + (size_t)er * 8);
        const float4 rb = *(const float4*)(rbase + (size_t)er * 8 + 4);

        // Metadata: local row (masked -1 for padded edges) + cutoff.
        int   lrow_e[4]; float cut_e[4];
        #pragma unroll
        for (int rg = 0; rg < 4; ++rg) {
            const int t_ = __shfl(__float_as_int(ra.y), g * 4 + rg);
            lrow_e[rg] = (base + g * 4 + rg < cnt) ? (t_ - node0) : -1;
            cut_e[rg]  = __shfl(rb.z, g * 4 + rg);
        }

        // Gather h1[src] directly in A-fragment layout (4 independent dwordx4).
        const int src = __float_as_int(ra.x);
        const float* hp = h1 + (size_t)src * F + g * 8;
        const float4 q00 = *(const float4*)(hp);
        const float4 q01 = *(const float4*)(hp + 4);
        const float4 q10 = *(const float4*)(hp + 32);
        const float4 q11 = *(const float4*)(hp + 36);

        float hv[2][8];
        hv[0][0] = q00.x; hv[0][1] = q00.y; hv[0][2] = q00.z; hv[0][3] = q00.w;
        hv[0][4] = q01.x; hv[0][5] = q01.y; hv[0][6] = q01.z; hv[0][7] = q01.w;
        hv[1][0] = q10.x; hv[1][1] = q10.y; hv[1][2] = q10.z; hv[1][3] = q10.w;
        hv[1][4] = q11.x; hv[1][5] = q11.y; hv[1][6] = q11.z; hv[1][7] = q11.w;

        // Rank-4 radial update + silu, then cvt to bf16 A-fragments.
        bf16x8 ah[2];
        #pragma unroll
        for (int t = 0; t < 2; ++t)
            #pragma unroll
            for (int j = 0; j < 8; ++j) {
                float h = hv[t][j];
                h = fmaf(ra.z, w1r[0][t][j], h);
                h = fmaf(ra.w, w1r[1][t][j], h);
                h = fmaf(rb.x, w1r[2][t][j], h);
                h = fmaf(rb.y, w1r[3][t][j], h);
                ah[t][j] = (short)bf16_rne(silu_f(h));
            }

        // [16 x 64] @ W2 via 8 MFMAs.
        f32x4 acc[4] = {};
        #pragma unroll
        for (int t = 0; t < 2; ++t)
            #pragma unroll
            for (int c = 0; c < 4; ++c)
                acc[c] = __builtin_amdgcn_mfma_f32_16x16x32_bf16(
                    ah[t], Bh[c][t], acc[c], 0, 0, 0);

        // A-fragment of P^T: A[r][k=4g+j] = (lrow_e[j] == r), exact 0/1.
        bf16x4 afrag;
        afrag[0] = (short)((lrow_e[0] == r) ? 0x3F80 : 0);
        afrag[1] = (short)((lrow_e[1] == r) ? 0x3F80 : 0);
        afrag[2] = (short)((lrow_e[2] == r) ? 0x3F80 : 0);
        afrag[3] = (short)((lrow_e[3] == r) ? 0x3F80 : 0);

        // E = silu(D2 + b2) * cut, hi/lo bf16 split; feed as B operand
        // (zero lane movement), accumulate aggr via 2 MFMAs per c.
        #pragma unroll
        for (int c = 0; c < 4; ++c) {
            float ef[4];
            #pragma unroll
            for (int rg = 0; rg < 4; ++rg)
                ef[rg] = silu_f(acc[c][rg] + b2c[c]) * cut_e[rg];

            bf16x4 beh, bel;
            #pragma unroll
            for (int rg = 0; rg < 4; ++rg) {
                const unsigned short hb = bf16_rne(ef[rg]);
                beh[rg] = (short)hb;
                bel[rg] = (short)bf16_rne(ef[rg] - bf16_f32(hb));
            }
            acc3[c] = mfma16k(afrag, beh, acc3[c]);
            acc3[c] = mfma16k(afrag, bel, acc3[c]);
        }
    }

    // Epilogue: wave-exclusive rows -> plain read-add-write (no atomics).
    // D3: lane (r,g) holds aggr[4g+rg][c*16+r].
    #pragma unroll
    for (int rg = 0; rg < 4; ++rg) {
        float* rowp = out + (size_t)(node0 + g * 4 + rg) * F;
        #pragma unroll
        for (int c = 0; c < 4; ++c) {
            rowp[c * 16 + r] += acc3[c][rg];
        }
    }
}

extern "C" void kernel_launch(void* const* d_in, const int* in_sizes, int n_in,
                              void* d_out, int out_size, void* d_ws, size_t ws_size,
                              hipStream_t stream) {
    const float* x   = (const float*)d_in[0];
    const int*   ei  = (const int*)d_in[1];
    const float* pos = (const float*)d_in[2];
    const float* Wp  = (const float*)d_in[3];
    const float* bp  = (const float*)d_in[4];
    const float* W1  = (const float*)d_in[5];
    const float* b1  = (const float*)d_in[6];
    const float* W2  = (const float*)d_in[7];
    const float* b2  = (const float*)d_in[8];
    const float* Wr1 = (const float*)d_in[9];
    const float* br1 = (const float*)d_in[10];
    const float* Wr2 = (const float*)d_in[11];
    const float* br2 = (const float*)d_in[12];
    float* out = (float*)d_out;

    // workspace: [counts 16KB][h1 12.8MB][recs 3125*160*32B = 16MB] ~ 29MB
    char*  ws     = (char*)d_ws;
    int*   counts = (int*)ws;
    float* h1     = (float*)(ws + 16384);
    float* recs   = (float*)(ws + 16384 + (size_t)N_NODES * F * sizeof(float));

    hipMemsetAsync(counts, 0, NBUCKET * sizeof(int), stream);
    node_kernel<<<NODE_BLOCKS, 256, 0, stream>>>(
        x, Wp, bp, W1, b1, out, h1);
    edge_prep_kernel<<<PREP_BLOCKS, 256, 0, stream>>>(
        ei, pos, Wr1, br1, Wr2, br2, recs, counts);
    edge_main_kernel<<<MAIN_BLOCKS, 256, 0, stream>>>(
        recs, counts, h1, W1, W2, b2, out);
}

// Round 12
// 74.988 us; speedup vs baseline: 1.2892x; 1.2892x over previous
//
#include <hip/hip_runtime.h>
#include <hip/hip_bf16.h>
#include <math.h>

#define N_NODES 50000
#define N_EDGES 800000
#define F 64
#define CUTOFF2 100.0f

#define NPB 8                  // nodes per bucket; bucket = tgt >> 3
#define NBUCKET 6250           // 50000 / 8 exactly
#define CAP 96                 // records/bucket (mean ~45, sigma ~6.7, +7.6 sigma)
#define NODE_BLOCKS 782        // ceil(3125 node-tiles / 4 waves)
#define PREP_BLOCKS 3125       // 800000 / 256 exactly
#define MAIN_BLOCKS 1563       // ceil(6250 buckets / 4 waves-per-block)

typedef __attribute__((ext_vector_type(8))) short bf16x8;   // 8 bf16 = 4 VGPR
typedef __attribute__((ext_vector_type(4))) short bf16x4;   // 4 bf16 = 2 VGPR
typedef __attribute__((ext_vector_type(4))) float f32x4;    // MFMA C/D

// Division-free silu (R10, verified): v * rcp(1 + exp(-v)).
__device__ __forceinline__ float silu_f(float v) {
    return v * __builtin_amdgcn_rcpf(1.0f + __expf(-v));
}

// f32 -> bf16 bits, round-to-nearest-even
__device__ __forceinline__ unsigned short bf16_rne(float f) {
    unsigned int u = __float_as_uint(f);
    unsigned int r = (u + 0x7FFFu + ((u >> 16) & 1u)) >> 16;
    return (unsigned short)r;
}
__device__ __forceinline__ float bf16_f32(unsigned int h) {
    return __uint_as_float(h << 16);
}

// K=16 bf16 MFMA (R11-verified on-device).
//   A: row = lane&15, k = (lane>>4)*4 + j
//   B: col = lane&15, k = (lane>>4)*4 + j   (== 16x16x32 D-row position)
//   D: col = lane&15, row = (lane>>4)*4 + reg
__device__ __forceinline__ f32x4 mfma16k(bf16x4 a, bf16x4 b, f32x4 c) {
#if __has_builtin(__builtin_amdgcn_mfma_f32_16x16x16bf16_1k)
    return __builtin_amdgcn_mfma_f32_16x16x16bf16_1k(a, b, c, 0, 0, 0);
#elif __has_builtin(__builtin_amdgcn_mfma_f32_16x16x16_bf16)
    return __builtin_amdgcn_mfma_f32_16x16x16_bf16(a, b, c, 0, 0, 0);
#else
    f32x4 d = c;
    asm volatile("v_mfma_f32_16x16x16_bf16 %0, %1, %2, %0"
                 : "+v"(d) : "v"(a), "v"(b));
    return d;
#endif
}

// ---------------------------------------------------------------------------
// 16-row GEMM tile vs 64x64 row-major W (3-term bf16 split ~ f32 accuracy).
// MFMA f32_16x16x32_bf16 layouts (refcheck-verified rounds 3-11):
//   A: row = lane&15, k = (lane>>4)*8 + j
//   B: col = lane&15, k = (lane>>4)*8 + j
//   D: col = lane&15, row = (lane>>4)*4 + reg
// ---------------------------------------------------------------------------
__device__ __forceinline__ void gemm16_store(
    const bf16x8 (&Ah)[2], const bf16x8 (&Al)[2],
    const float* __restrict__ W, const float* __restrict__ bias,
    float* __restrict__ dst, int n0, int r, int g)
{
    #pragma unroll
    for (int c = 0; c < 4; ++c) {
        f32x4 acc = {0.f, 0.f, 0.f, 0.f};
        #pragma unroll
        for (int t = 0; t < 2; ++t) {
            bf16x8 bh, bl;
            #pragma unroll
            for (int j = 0; j < 8; ++j) {
                const float wv = W[(size_t)(t * 32 + g * 8 + j) * F + c * 16 + r];
                const unsigned short hb = bf16_rne(wv);
                bh[j] = (short)hb;
                bl[j] = (short)bf16_rne(wv - bf16_f32(hb));
            }
            acc = __builtin_amdgcn_mfma_f32_16x16x32_bf16(Ah[t], bh, acc, 0, 0, 0);
            acc = __builtin_amdgcn_mfma_f32_16x16x32_bf16(Al[t], bh, acc, 0, 0, 0);
            acc = __builtin_amdgcn_mfma_f32_16x16x32_bf16(Ah[t], bl, acc, 0, 0, 0);
        }
        const float bb = bias[c * 16 + r];
        #pragma unroll
        for (int rg = 0; rg < 4; ++rg) {
            dst[(size_t)(n0 + g * 4 + rg) * F + c * 16 + r] = acc[rg] + bb;
        }
    }
}

// ---------------------------------------------------------------------------
// Kernel 1 (fused): blocks [0, NODE_BLOCKS) node projections via MFMA;
// blocks [NODE_BLOCKS, ...) edge prep: cutoff + radial MLP + bin-by-bucket.
// R12 record (16B, was 32B): {src|lrow<<16, bf16 r0|r1, bf16 r2|r3, f32 cut}
//  - src < 50000 < 2^16 fits u16; lrow = tgt & 7
//  - bf16 radial: error << the existing bf16 A-fragment rounding
//  - ONE scattered 16B store per edge (was two) -> half prep's line-RMWs
// ---------------------------------------------------------------------------
__global__ __launch_bounds__(256) void node_prep_kernel(
    const float* __restrict__ x, const float* __restrict__ Wp,
    const float* __restrict__ bp, const float* __restrict__ W1,
    const float* __restrict__ b1,
    const int* __restrict__ ei, const float* __restrict__ pos,
    const float* __restrict__ Wr1, const float* __restrict__ br1,
    const float* __restrict__ Wr2, const float* __restrict__ br2,
    float* __restrict__ out, float* __restrict__ h1,
    unsigned int* __restrict__ recs, int* __restrict__ counts)
{
    if (blockIdx.x < NODE_BLOCKS) {
        const int lane = threadIdx.x & 63;
        const int gw   = blockIdx.x * 4 + (threadIdx.x >> 6);
        if (gw >= N_NODES / 16) return;
        const int n0 = gw * 16;
        const int r = lane & 15, g = lane >> 4;

        bf16x8 Ah[2], Al[2];
        #pragma unroll
        for (int t = 0; t < 2; ++t) {
            const float* xp = x + (size_t)(n0 + r) * F + t * 32 + g * 8;
            #pragma unroll
            for (int j = 0; j < 8; ++j) {
                const float v = xp[j];
                const unsigned short hb = bf16_rne(v);
                Ah[t][j] = (short)hb;
                Al[t][j] = (short)bf16_rne(v - bf16_f32(hb));
            }
        }
        gemm16_store(Ah, Al, Wp, bp, out, n0, r, g);
        gemm16_store(Ah, Al, W1, b1, h1, n0, r, g);
    } else {
        const int e = (blockIdx.x - NODE_BLOCKS) * 256 + threadIdx.x; // exact
        const int src = ei[e];
        const int tgt = ei[N_EDGES + e];
        const float dx = pos[3 * tgt + 0] - pos[3 * src + 0];
        const float dy = pos[3 * tgt + 1] - pos[3 * src + 1];
        const float dz = pos[3 * tgt + 2] - pos[3 * src + 2];
        const float d2 = dx * dx + dy * dy + dz * dz;
        if (d2 >= CUTOFF2) return;

        const float d = sqrtf(d2);
        float a0 = br2[0], a1 = br2[1], a2 = br2[2], a3 = br2[3];
        #pragma unroll
        for (int i = 0; i < 16; ++i) {
            const float t = silu_f(fmaf(d, Wr1[i], br1[i]));
            a0 = fmaf(t, Wr2[i * 4 + 0], a0);
            a1 = fmaf(t, Wr2[i * 4 + 1], a1);
            a2 = fmaf(t, Wr2[i * 4 + 2], a2);
            a3 = fmaf(t, Wr2[i * 4 + 3], a3);
        }
        const float cut = 1.0f - d2 * 0.01f;    // in (0,1] when d2 < 100

        const int b   = tgt >> 3;               // NPB = 8
        const int idx = atomicAdd(&counts[b], 1);
        if (idx < CAP) {
            uint4 rec;
            rec.x = (unsigned)src | ((unsigned)(tgt & 7) << 16);
            rec.y = (unsigned)bf16_rne(silu_f(a0))
                  | ((unsigned)bf16_rne(silu_f(a1)) << 16);
            rec.z = (unsigned)bf16_rne(silu_f(a2))
                  | ((unsigned)bf16_rne(silu_f(a3)) << 16);
            rec.w = __float_as_uint(cut);
            *(uint4*)(recs + ((size_t)b * CAP + idx) * 4) = rec;
        }
    }
}

// ---------------------------------------------------------------------------
// Kernel 2 (R12): zero-atomic edge MLP, one WAVE per 8-node bucket.
// NPB 16->8 doubles wave count (6250 waves, ~6.1/SIMD nominal) for TLP
// latency hiding of the record->h1 dependent chain (R11: occupancy 16%,
// 1.3 waves/SIMD resident, latency-exposed).
// Aggregation: aggr[16x64] += P^T @ E via mfma_16x16x16_bf16 (R11-verified;
// rows 8..15 never match -> zero). Epilogue guarded g<2: rows node0+8..15
// belong to the NEIGHBOR bucket's wave (race if touched).
// ---------------------------------------------------------------------------
__global__ __launch_bounds__(256, 3) void edge_main_kernel(
    const unsigned int* __restrict__ recs, const int* __restrict__ counts,
    const float* __restrict__ h1, const float* __restrict__ W1,
    const float* __restrict__ W2, const float* __restrict__ b2,
    float* __restrict__ out)
{
    const int lane = threadIdx.x & 63;
    const int w    = threadIdx.x >> 6;
    const int r    = lane & 15, g = lane >> 4;

    const int bkt = blockIdx.x * 4 + w;
    if (bkt >= NBUCKET) return;
    const int cnt = min(counts[bkt], CAP);
    if (cnt == 0) return;                 // wave-uniform; rows keep node term

    // W2 B-fragments, bf16 single term (32 VGPRs). L2-hot across all waves.
    bf16x8 Bh[4][2];
    #pragma unroll
    for (int c = 0; c < 4; ++c)
        #pragma unroll
        for (int t = 0; t < 2; ++t)
            #pragma unroll
            for (int jj = 0; jj < 8; ++jj)
                Bh[c][t][jj] = (short)bf16_rne(
                    W2[(size_t)(t * 32 + g * 8 + jj) * F + c * 16 + r]);

    // W1 radial rows 64..67, this lane's k-slice (64 VGPRs, f32).
    float w1r[4][2][8];
    #pragma unroll
    for (int i = 0; i < 4; ++i)
        #pragma unroll
        for (int t = 0; t < 2; ++t) {
            const float4 wa = *(const float4*)&W1[(size_t)(F + i) * F + t * 32 + g * 8];
            const float4 wb = *(const float4*)&W1[(size_t)(F + i) * F + t * 32 + g * 8 + 4];
            w1r[i][t][0] = wa.x; w1r[i][t][1] = wa.y;
            w1r[i][t][2] = wa.z; w1r[i][t][3] = wa.w;
            w1r[i][t][4] = wb.x; w1r[i][t][5] = wb.y;
            w1r[i][t][6] = wb.z; w1r[i][t][7] = wb.w;
        }

    float b2c[4];
    #pragma unroll
    for (int c = 0; c < 4; ++c) b2c[c] = b2[c * 16 + r];

    const int node0 = bkt * NPB;
    const unsigned int* rbase = recs + (size_t)bkt * CAP * 4;
    const int ntiles = (cnt + 15) >> 4;

    f32x4 acc3[4] = {};   // output-stationary: aggr[4g+rg][c*16+r]

    for (int s = 0; s < ntiles; ++s) {
        const int base = s << 4;
        // Branch-free 16B record load: all 64 lanes load edge (base + r).
        const int er = min(base + r, cnt - 1);
        const uint4 rec = *(const uint4*)(rbase + (size_t)er * 4);
        const int   src  = (int)(rec.x & 0xFFFFu);
        const int   lrow = (int)(rec.x >> 16);
        const float rr0  = bf16_f32(rec.y & 0xFFFFu);
        const float rr1  = bf16_f32(rec.y >> 16);
        const float rr2  = bf16_f32(rec.z & 0xFFFFu);
        const float rr3  = bf16_f32(rec.z >> 16);
        const float cut  = __uint_as_float(rec.w);

        // Metadata: local row (masked -1 for padded edges) + cutoff.
        int   lrow_e[4]; float cut_e[4];
        #pragma unroll
        for (int rg = 0; rg < 4; ++rg) {
            const int lr = __shfl(lrow, g * 4 + rg);
            lrow_e[rg] = (base + g * 4 + rg < cnt) ? lr : -1;
            cut_e[rg]  = __shfl(cut, g * 4 + rg);
        }

        // Gather h1[src] directly in A-fragment layout (4 independent dwordx4).
        const float* hp = h1 + (size_t)src * F + g * 8;
        const float4 q00 = *(const float4*)(hp);
        const float4 q01 = *(const float4*)(hp + 4);
        const float4 q10 = *(const float4*)(hp + 32);
        const float4 q11 = *(const float4*)(hp + 36);

        float hv[2][8];
        hv[0][0] = q00.x; hv[0][1] = q00.y; hv[0][2] = q00.z; hv[0][3] = q00.w;
        hv[0][4] = q01.x; hv[0][5] = q01.y; hv[0][6] = q01.z; hv[0][7] = q01.w;
        hv[1][0] = q10.x; hv[1][1] = q10.y; hv[1][2] = q10.z; hv[1][3] = q10.w;
        hv[1][4] = q11.x; hv[1][5] = q11.y; hv[1][6] = q11.z; hv[1][7] = q11.w;

        // Rank-4 radial update + silu, then cvt to bf16 A-fragments.
        bf16x8 ah[2];
        #pragma unroll
        for (int t = 0; t < 2; ++t)
            #pragma unroll
            for (int j = 0; j < 8; ++j) {
                float h = hv[t][j];
                h = fmaf(rr0, w1r[0][t][j], h);
                h = fmaf(rr1, w1r[1][t][j], h);
                h = fmaf(rr2, w1r[2][t][j], h);
                h = fmaf(rr3, w1r[3][t][j], h);
                ah[t][j] = (short)bf16_rne(silu_f(h));
            }

        // [16 x 64] @ W2 via 8 MFMAs.
        f32x4 acc[4] = {};
        #pragma unroll
        for (int t = 0; t < 2; ++t)
            #pragma unroll
            for (int c = 0; c < 4; ++c)
                acc[c] = __builtin_amdgcn_mfma_f32_16x16x32_bf16(
                    ah[t], Bh[c][t], acc[c], 0, 0, 0);

        // A-fragment of P^T: A[r][k=4g+j] = (lrow_e[j] == r), exact 0/1.
        bf16x4 afrag;
        afrag[0] = (short)((lrow_e[0] == r) ? 0x3F80 : 0);
        afrag[1] = (short)((lrow_e[1] == r) ? 0x3F80 : 0);
        afrag[2] = (short)((lrow_e[2] == r) ? 0x3F80 : 0);
        afrag[3] = (short)((lrow_e[3] == r) ? 0x3F80 : 0);

        // E = silu(D2 + b2) * cut, hi/lo bf16 split; zero-lane-movement
        // B-operand feed; accumulate aggr via 2 MFMAs per c.
        #pragma unroll
        for (int c = 0; c < 4; ++c) {
            float ef[4];
            #pragma unroll
            for (int rg = 0; rg < 4; ++rg)
                ef[rg] = silu_f(acc[c][rg] + b2c[c]) * cut_e[rg];

            bf16x4 beh, bel;
            #pragma unroll
            for (int rg = 0; rg < 4; ++rg) {
                const unsigned short hb = bf16_rne(ef[rg]);
                beh[rg] = (short)hb;
                bel[rg] = (short)bf16_rne(ef[rg] - bf16_f32(hb));
            }
            acc3[c] = mfma16k(afrag, beh, acc3[c]);
            acc3[c] = mfma16k(afrag, bel, acc3[c]);
        }
    }

    // Epilogue: wave-exclusive rows [node0, node0+8) -> plain read-add-write.
    // g >= 2 holds rows 8..15 which are always zero AND belong to the
    // neighbor bucket -> must not touch (race).
    if (g < 2) {
        #pragma unroll
        for (int rg = 0; rg < 4; ++rg) {
            float* rowp = out + (size_t)(node0 + g * 4 + rg) * F;
            #pragma unroll
            for (int c = 0; c < 4; ++c) {
                rowp[c * 16 + r] += acc3[c][rg];
            }
        }
    }
}

extern "C" void kernel_launch(void* const* d_in, const int* in_sizes, int n_in,
                              void* d_out, int out_size, void* d_ws, size_t ws_size,
                              hipStream_t stream) {
    const float* x   = (const float*)d_in[0];
    const int*   ei  = (const int*)d_in[1];
    const float* pos = (const float*)d_in[2];
    const float* Wp  = (const float*)d_in[3];
    const float* bp  = (const float*)d_in[4];
    const float* W1  = (const float*)d_in[5];
    const float* b1  = (const float*)d_in[6];
    const float* W2  = (const float*)d_in[7];
    const float* b2  = (const float*)d_in[8];
    const float* Wr1 = (const float*)d_in[9];
    const float* br1 = (const float*)d_in[10];
    const float* Wr2 = (const float*)d_in[11];
    const float* br2 = (const float*)d_in[12];
    float* out = (float*)d_out;

    // workspace: [counts 32KB][h1 12.8MB][recs 6250*96*16B = 9.6MB] ~ 22.4MB
    char*         ws     = (char*)d_ws;
    int*          counts = (int*)ws;
    float*        h1     = (float*)(ws + 32768);
    unsigned int* recs   = (unsigned int*)(ws + 32768
                               + (size_t)N_NODES * F * sizeof(float));

    hipMemsetAsync(counts, 0, NBUCKET * sizeof(int), stream);
    node_prep_kernel<<<NODE_BLOCKS + PREP_BLOCKS, 256, 0, stream>>>(
        x, Wp, bp, W1, b1, ei, pos, Wr1, br1, Wr2, br2,
        out, h1, recs, counts);
    edge_main_kernel<<<MAIN_BLOCKS, 256, 0, stream>>>(
        recs, counts, h1, W1, W2, b2, out);
}

// Round 13
// 69.839 us; speedup vs baseline: 1.3843x; 1.0737x over previous
//
#include <hip/hip_runtime.h>
#include <hip/hip_bf16.h>
#include <math.h>

#define N_NODES 50000
#define N_EDGES 800000
#define F 64
#define CUTOFF2 100.0f

#define NPB 8                  // nodes per bucket; bucket = tgt >> 3
#define NBUCKET 6250           // 50000 / 8 exactly
#define CAP 96                 // records/bucket (mean ~45, sigma ~6.7)
#define NODE_BLOCKS 782        // ceil(3125 node-tiles / 4 waves)
#define PREP_BLOCKS 3125       // 800000 / 256 exactly
#define MAIN_BLOCKS 1563       // ceil(6250 buckets / 4 waves-per-block)

typedef __attribute__((ext_vector_type(8))) short bf16x8;   // 8 bf16 = 4 VGPR
typedef __attribute__((ext_vector_type(4))) short bf16x4;   // 4 bf16 = 2 VGPR
typedef __attribute__((ext_vector_type(4))) float f32x4;    // MFMA C/D

// Division-free silu (R10, verified): v * rcp(1 + exp(-v)).
__device__ __forceinline__ float silu_f(float v) {
    return v * __builtin_amdgcn_rcpf(1.0f + __expf(-v));
}

// f32 -> bf16 bits, round-to-nearest-even
__device__ __forceinline__ unsigned short bf16_rne(float f) {
    unsigned int u = __float_as_uint(f);
    unsigned int r = (u + 0x7FFFu + ((u >> 16) & 1u)) >> 16;
    return (unsigned short)r;
}
__device__ __forceinline__ float bf16_f32(unsigned int h) {
    return __uint_as_float(h << 16);
}

// K=16 bf16 MFMA (R11/R12-verified on-device).
//   A: row = lane&15, k = (lane>>4)*4 + j
//   B: col = lane&15, k = (lane>>4)*4 + j   (== 16x16x32 D-row position)
//   D: col = lane&15, row = (lane>>4)*4 + reg
__device__ __forceinline__ f32x4 mfma16k(bf16x4 a, bf16x4 b, f32x4 c) {
#if __has_builtin(__builtin_amdgcn_mfma_f32_16x16x16bf16_1k)
    return __builtin_amdgcn_mfma_f32_16x16x16bf16_1k(a, b, c, 0, 0, 0);
#elif __has_builtin(__builtin_amdgcn_mfma_f32_16x16x16_bf16)
    return __builtin_amdgcn_mfma_f32_16x16x16_bf16(a, b, c, 0, 0, 0);
#else
    f32x4 d = c;
    asm volatile("v_mfma_f32_16x16x16_bf16 %0, %1, %2, %0"
                 : "+v"(d) : "v"(a), "v"(b));
    return d;
#endif
}

// ---------------------------------------------------------------------------
// 16-row GEMM tile vs 64x64 row-major W (3-term bf16 split ~ f32 accuracy).
// MFMA f32_16x16x32_bf16 layouts (refcheck-verified rounds 3-12):
//   A: row = lane&15, k = (lane>>4)*8 + j
//   B: col = lane&15, k = (lane>>4)*8 + j
//   D: col = lane&15, row = (lane>>4)*4 + reg
// ---------------------------------------------------------------------------
__device__ __forceinline__ void gemm16_store(
    const bf16x8 (&Ah)[2], const bf16x8 (&Al)[2],
    const float* __restrict__ W, const float* __restrict__ bias,
    float* __restrict__ dst, int n0, int r, int g)
{
    #pragma unroll
    for (int c = 0; c < 4; ++c) {
        f32x4 acc = {0.f, 0.f, 0.f, 0.f};
        #pragma unroll
        for (int t = 0; t < 2; ++t) {
            bf16x8 bh, bl;
            #pragma unroll
            for (int j = 0; j < 8; ++j) {
                const float wv = W[(size_t)(t * 32 + g * 8 + j) * F + c * 16 + r];
                const unsigned short hb = bf16_rne(wv);
                bh[j] = (short)hb;
                bl[j] = (short)bf16_rne(wv - bf16_f32(hb));
            }
            acc = __builtin_amdgcn_mfma_f32_16x16x32_bf16(Ah[t], bh, acc, 0, 0, 0);
            acc = __builtin_amdgcn_mfma_f32_16x16x32_bf16(Al[t], bh, acc, 0, 0, 0);
            acc = __builtin_amdgcn_mfma_f32_16x16x32_bf16(Ah[t], bl, acc, 0, 0, 0);
        }
        const float bb = bias[c * 16 + r];
        #pragma unroll
        for (int rg = 0; rg < 4; ++rg) {
            dst[(size_t)(n0 + g * 4 + rg) * F + c * 16 + r] = acc[rg] + bb;
        }
    }
}

// ---------------------------------------------------------------------------
// Kernel 1 (fused): node projections + edge prep (unchanged from R12).
// R12 record (16B): {src|lrow<<16, bf16 r0|r1, bf16 r2|r3, f32 cut}
// ---------------------------------------------------------------------------
__global__ __launch_bounds__(256) void node_prep_kernel(
    const float* __restrict__ x, const float* __restrict__ Wp,
    const float* __restrict__ bp, const float* __restrict__ W1,
    const float* __restrict__ b1,
    const int* __restrict__ ei, const float* __restrict__ pos,
    const float* __restrict__ Wr1, const float* __restrict__ br1,
    const float* __restrict__ Wr2, const float* __restrict__ br2,
    float* __restrict__ out, float* __restrict__ h1,
    unsigned int* __restrict__ recs, int* __restrict__ counts)
{
    if (blockIdx.x < NODE_BLOCKS) {
        const int lane = threadIdx.x & 63;
        const int gw   = blockIdx.x * 4 + (threadIdx.x >> 6);
        if (gw >= N_NODES / 16) return;
        const int n0 = gw * 16;
        const int r = lane & 15, g = lane >> 4;

        bf16x8 Ah[2], Al[2];
        #pragma unroll
        for (int t = 0; t < 2; ++t) {
            const float* xp = x + (size_t)(n0 + r) * F + t * 32 + g * 8;
            #pragma unroll
            for (int j = 0; j < 8; ++j) {
                const float v = xp[j];
                const unsigned short hb = bf16_rne(v);
                Ah[t][j] = (short)hb;
                Al[t][j] = (short)bf16_rne(v - bf16_f32(hb));
            }
        }
        gemm16_store(Ah, Al, Wp, bp, out, n0, r, g);
        gemm16_store(Ah, Al, W1, b1, h1, n0, r, g);
    } else {
        const int e = (blockIdx.x - NODE_BLOCKS) * 256 + threadIdx.x; // exact
        const int src = ei[e];
        const int tgt = ei[N_EDGES + e];
        const float dx = pos[3 * tgt + 0] - pos[3 * src + 0];
        const float dy = pos[3 * tgt + 1] - pos[3 * src + 1];
        const float dz = pos[3 * tgt + 2] - pos[3 * src + 2];
        const float d2 = dx * dx + dy * dy + dz * dz;
        if (d2 >= CUTOFF2) return;

        const float d = sqrtf(d2);
        float a0 = br2[0], a1 = br2[1], a2 = br2[2], a3 = br2[3];
        #pragma unroll
        for (int i = 0; i < 16; ++i) {
            const float t = silu_f(fmaf(d, Wr1[i], br1[i]));
            a0 = fmaf(t, Wr2[i * 4 + 0], a0);
            a1 = fmaf(t, Wr2[i * 4 + 1], a1);
            a2 = fmaf(t, Wr2[i * 4 + 2], a2);
            a3 = fmaf(t, Wr2[i * 4 + 3], a3);
        }
        const float cut = 1.0f - d2 * 0.01f;    // in (0,1] when d2 < 100

        const int b   = tgt >> 3;               // NPB = 8
        const int idx = atomicAdd(&counts[b], 1);
        if (idx < CAP) {
            uint4 rec;
            rec.x = (unsigned)src | ((unsigned)(tgt & 7) << 16);
            rec.y = (unsigned)bf16_rne(silu_f(a0))
                  | ((unsigned)bf16_rne(silu_f(a1)) << 16);
            rec.z = (unsigned)bf16_rne(silu_f(a2))
                  | ((unsigned)bf16_rne(silu_f(a3)) << 16);
            rec.w = __float_as_uint(cut);
            *(uint4*)(recs + ((size_t)b * CAP + idx) * 4) = rec;
        }
    }
}

// Per-tile in-flight state for the 2-chain ILP pipeline (named fields only,
// rule #20: no runtime-indexed arrays).
struct TileIn {
    uint4  rec;
    float4 q00, q01, q10, q11;
};

__device__ __forceinline__ TileIn load_tile(
    const unsigned int* __restrict__ rbase, const float* __restrict__ h1,
    int base, int r, int g, int cnt)
{
    TileIn ti;
    const int er = min(base + r, cnt - 1);
    ti.rec = *(const uint4*)(rbase + (size_t)er * 4);
    const int src = (int)(ti.rec.x & 0xFFFFu);
    const float* hp = h1 + (size_t)src * F + g * 8;
    ti.q00 = *(const float4*)(hp);
    ti.q01 = *(const float4*)(hp + 4);
    ti.q10 = *(const float4*)(hp + 32);
    ti.q11 = *(const float4*)(hp + 36);
    return ti;
}

// ---------------------------------------------------------------------------
// Kernel 2 (R13): zero-atomic edge MLP with 2-tile ILP.
// Evidence: R11->R12 doubled waves with ZERO time change -> main is bound by
// per-tile exposed latency (rec->shfl->gather chain, ~1300cy) that TLP never
// covers (effective ~1.5 waves/SIMD regardless of launch). Buy the overlap
// with ILP instead: two independent tile-chains per iteration, both loads
// issued before either compute. Phantom tiles (base>=cnt) are exactly
// masked by lrow=-1 -> afrag=0 (verified mechanism, R11/R12).
// ---------------------------------------------------------------------------
__global__ __launch_bounds__(256, 2) void edge_main_kernel(
    const unsigned int* __restrict__ recs, const int* __restrict__ counts,
    const float* __restrict__ h1, const float* __restrict__ W1,
    const float* __restrict__ W2, const float* __restrict__ b2,
    float* __restrict__ out)
{
    const int lane = threadIdx.x & 63;
    const int w    = threadIdx.x >> 6;
    const int r    = lane & 15, g = lane >> 4;

    const int bkt = blockIdx.x * 4 + w;
    if (bkt >= NBUCKET) return;
    const int cnt = min(counts[bkt], CAP);
    if (cnt == 0) return;                 // wave-uniform; rows keep node term

    // W2 B-fragments, bf16 single term (32 VGPRs). L2-hot across all waves.
    bf16x8 Bh[4][2];
    #pragma unroll
    for (int c = 0; c < 4; ++c)
        #pragma unroll
        for (int t = 0; t < 2; ++t)
            #pragma unroll
            for (int jj = 0; jj < 8; ++jj)
                Bh[c][t][jj] = (short)bf16_rne(
                    W2[(size_t)(t * 32 + g * 8 + jj) * F + c * 16 + r]);

    // W1 radial rows 64..67, this lane's k-slice (64 VGPRs, f32).
    float w1r[4][2][8];
    #pragma unroll
    for (int i = 0; i < 4; ++i)
        #pragma unroll
        for (int t = 0; t < 2; ++t) {
            const float4 wa = *(const float4*)&W1[(size_t)(F + i) * F + t * 32 + g * 8];
            const float4 wb = *(const float4*)&W1[(size_t)(F + i) * F + t * 32 + g * 8 + 4];
            w1r[i][t][0] = wa.x; w1r[i][t][1] = wa.y;
            w1r[i][t][2] = wa.z; w1r[i][t][3] = wa.w;
            w1r[i][t][4] = wb.x; w1r[i][t][5] = wb.y;
            w1r[i][t][6] = wb.z; w1r[i][t][7] = wb.w;
        }

    float b2c[4];
    #pragma unroll
    for (int c = 0; c < 4; ++c) b2c[c] = b2[c * 16 + r];

    const int node0 = bkt * NPB;
    const unsigned int* rbase = recs + (size_t)bkt * CAP * 4;
    const int ntiles = (cnt + 15) >> 4;

    f32x4 acc3[4] = {};   // output-stationary: aggr[4g+rg][c*16+r]

    // Tile-compute macro-equivalent as a lambda over named state.
    auto compute_tile = [&](const TileIn& ti, int base) {
        const int   lrow = (int)(ti.rec.x >> 16);
        const float rr0  = bf16_f32(ti.rec.y & 0xFFFFu);
        const float rr1  = bf16_f32(ti.rec.y >> 16);
        const float rr2  = bf16_f32(ti.rec.z & 0xFFFFu);
        const float rr3  = bf16_f32(ti.rec.z >> 16);
        const float cut  = __uint_as_float(ti.rec.w);

        int   lrow_e[4]; float cut_e[4];
        #pragma unroll
        for (int rg = 0; rg < 4; ++rg) {
            const int lr = __shfl(lrow, g * 4 + rg);
            lrow_e[rg] = (base + g * 4 + rg < cnt) ? lr : -1;
            cut_e[rg]  = __shfl(cut, g * 4 + rg);
        }

        float hv[2][8];
        hv[0][0] = ti.q00.x; hv[0][1] = ti.q00.y; hv[0][2] = ti.q00.z; hv[0][3] = ti.q00.w;
        hv[0][4] = ti.q01.x; hv[0][5] = ti.q01.y; hv[0][6] = ti.q01.z; hv[0][7] = ti.q01.w;
        hv[1][0] = ti.q10.x; hv[1][1] = ti.q10.y; hv[1][2] = ti.q10.z; hv[1][3] = ti.q10.w;
        hv[1][4] = ti.q11.x; hv[1][5] = ti.q11.y; hv[1][6] = ti.q11.z; hv[1][7] = ti.q11.w;

        bf16x8 ah[2];
        #pragma unroll
        for (int t = 0; t < 2; ++t)
            #pragma unroll
            for (int j = 0; j < 8; ++j) {
                float h = hv[t][j];
                h = fmaf(rr0, w1r[0][t][j], h);
                h = fmaf(rr1, w1r[1][t][j], h);
                h = fmaf(rr2, w1r[2][t][j], h);
                h = fmaf(rr3, w1r[3][t][j], h);
                ah[t][j] = (short)bf16_rne(silu_f(h));
            }

        f32x4 acc[4] = {};
        #pragma unroll
        for (int t = 0; t < 2; ++t)
            #pragma unroll
            for (int c = 0; c < 4; ++c)
                acc[c] = __builtin_amdgcn_mfma_f32_16x16x32_bf16(
                    ah[t], Bh[c][t], acc[c], 0, 0, 0);

        bf16x4 afrag;
        afrag[0] = (short)((lrow_e[0] == r) ? 0x3F80 : 0);
        afrag[1] = (short)((lrow_e[1] == r) ? 0x3F80 : 0);
        afrag[2] = (short)((lrow_e[2] == r) ? 0x3F80 : 0);
        afrag[3] = (short)((lrow_e[3] == r) ? 0x3F80 : 0);

        #pragma unroll
        for (int c = 0; c < 4; ++c) {
            float ef[4];
            #pragma unroll
            for (int rg = 0; rg < 4; ++rg)
                ef[rg] = silu_f(acc[c][rg] + b2c[c]) * cut_e[rg];

            bf16x4 beh, bel;
            #pragma unroll
            for (int rg = 0; rg < 4; ++rg) {
                const unsigned short hb = bf16_rne(ef[rg]);
                beh[rg] = (short)hb;
                bel[rg] = (short)bf16_rne(ef[rg] - bf16_f32(hb));
            }
            acc3[c] = mfma16k(afrag, beh, acc3[c]);
            acc3[c] = mfma16k(afrag, bel, acc3[c]);
        }
    };

    // 2-tile ILP loop: both loads issued before either compute. Tile b1
    // past ntiles is a phantom (contributes exactly zero via afrag=0).
    for (int s = 0; s < ntiles; s += 2) {
        const int baseA = s << 4;
        const int baseB = (s + 1) << 4;
        const TileIn tA = load_tile(rbase, h1, baseA, r, g, cnt);
        const TileIn tB = load_tile(rbase, h1, baseB, r, g, cnt);
        compute_tile(tA, baseA);
        compute_tile(tB, baseB);
    }

    // Epilogue: wave-exclusive rows [node0, node0+8) -> plain read-add-write.
    // g >= 2 rows belong to the neighbor bucket (race if touched).
    if (g < 2) {
        #pragma unroll
        for (int rg = 0; rg < 4; ++rg) {
            float* rowp = out + (size_t)(node0 + g * 4 + rg) * F;
            #pragma unroll
            for (int c = 0; c < 4; ++c) {
                rowp[c * 16 + r] += acc3[c][rg];
            }
        }
    }
}

extern "C" void kernel_launch(void* const* d_in, const int* in_sizes, int n_in,
                              void* d_out, int out_size, void* d_ws, size_t ws_size,
                              hipStream_t stream) {
    const float* x   = (const float*)d_in[0];
    const int*   ei  = (const int*)d_in[1];
    const float* pos = (const float*)d_in[2];
    const float* Wp  = (const float*)d_in[3];
    const float* bp  = (const float*)d_in[4];
    const float* W1  = (const float*)d_in[5];
    const float* b1  = (const float*)d_in[6];
    const float* W2  = (const float*)d_in[7];
    const float* b2  = (const float*)d_in[8];
    const float* Wr1 = (const float*)d_in[9];
    const float* br1 = (const float*)d_in[10];
    const float* Wr2 = (const float*)d_in[11];
    const float* br2 = (const float*)d_in[12];
    float* out = (float*)d_out;

    // workspace: [counts 32KB][h1 12.8MB][recs 6250*96*16B = 9.6MB]
    char*         ws     = (char*)d_ws;
    int*          counts = (int*)ws;
    float*        h1     = (float*)(ws + 32768);
    unsigned int* recs   = (unsigned int*)(ws + 32768
                               + (size_t)N_NODES * F * sizeof(float));

    hipMemsetAsync(counts, 0, NBUCKET * sizeof(int), stream);
    node_prep_kernel<<<NODE_BLOCKS + PREP_BLOCKS, 256, 0, stream>>>(
        x, Wp, bp, W1, b1, ei, pos, Wr1, br1, Wr2, br2,
        out, h1, recs, counts);
    edge_main_kernel<<<MAIN_BLOCKS, 256, 0, stream>>>(
        recs, counts, h1, W1, W2, b2, out);
}

// Round 14
// 65.046 us; speedup vs baseline: 1.4862x; 1.0737x over previous
//
#include <hip/hip_runtime.h>
#include <hip/hip_bf16.h>
#include <math.h>

#define N_NODES 50000
#define N_EDGES 800000
#define F 64
#define CUTOFF2 100.0f

#define NPB 8                  // nodes per bucket; bucket = tgt >> 3
#define NBUCKET 6250           // 50000 / 8 exactly
#define CAP 96                 // records/bucket (mean ~45, sigma ~6.7)
#define NODE_BLOCKS 782        // ceil(3125 node-tiles / 4 waves)
#define PREP_BLOCKS 3125       // 800000 / 256 exactly
#define MAIN_BLOCKS 1563       // ceil(6250 buckets / 4 waves-per-block)

typedef __attribute__((ext_vector_type(8))) short    bf16x8;  // node GEMM path
typedef __attribute__((ext_vector_type(8))) _Float16 f16x8;   // edge pipeline
typedef __attribute__((ext_vector_type(4))) _Float16 f16x4;
typedef __attribute__((ext_vector_type(4))) float    f32x4;   // MFMA C/D

// Division-free silu (R10, verified): v * rcp(1 + exp(-v)).
__device__ __forceinline__ float silu_f(float v) {
    return v * __builtin_amdgcn_rcpf(1.0f + __expf(-v));
}

// f32 -> bf16 bits, round-to-nearest-even (node GEMM 3-term path)
__device__ __forceinline__ unsigned short bf16_rne(float f) {
    unsigned int u = __float_as_uint(f);
    unsigned int r = (u + 0x7FFFu + ((u >> 16) & 1u)) >> 16;
    return (unsigned short)r;
}
__device__ __forceinline__ float bf16_f32(unsigned int h) {
    return __uint_as_float(h << 16);
}

// fp16 bit helpers
__device__ __forceinline__ unsigned short f16_bits(float f) {
    _Float16 h = (_Float16)f;
    return __builtin_bit_cast(unsigned short, h);
}
__device__ __forceinline__ float f16_f32(unsigned short b) {
    return (float)__builtin_bit_cast(_Float16, b);
}

// K=16 f16 MFMA (aggregation). Layouts (canonical CDNA 16x16x16):
//   A: row = lane&15, k = (lane>>4)*4 + j
//   B: col = lane&15, k = (lane>>4)*4 + j   (== 16x16x32 D-row position)
//   D: col = lane&15, row = (lane>>4)*4 + reg
__device__ __forceinline__ f32x4 mfma16k_f16(f16x4 a, f16x4 b, f32x4 c) {
#if __has_builtin(__builtin_amdgcn_mfma_f32_16x16x16f16)
    return __builtin_amdgcn_mfma_f32_16x16x16f16(a, b, c, 0, 0, 0);
#elif __has_builtin(__builtin_amdgcn_mfma_f32_16x16x16_f16)
    return __builtin_amdgcn_mfma_f32_16x16x16_f16(a, b, c, 0, 0, 0);
#else
    f32x4 d = c;
    asm volatile("v_mfma_f32_16x16x16_f16 %0, %1, %2, %0"
                 : "+v"(d) : "v"(a), "v"(b));
    return d;
#endif
}

// ---------------------------------------------------------------------------
// 16-row GEMM tile vs 64x64 row-major W (3-term bf16 split ~ f32 accuracy).
// MFMA f32_16x16x32_bf16 layouts (refcheck-verified rounds 3-13):
//   A: row = lane&15, k = (lane>>4)*8 + j
//   B: col = lane&15, k = (lane>>4)*8 + j
//   D: col = lane&15, row = (lane>>4)*4 + reg
// Two variants: f32 store (out) and fp16 store (h1).
// ---------------------------------------------------------------------------
__device__ __forceinline__ void gemm16_store(
    const bf16x8 (&Ah)[2], const bf16x8 (&Al)[2],
    const float* __restrict__ W, const float* __restrict__ bias,
    float* __restrict__ dst, int n0, int r, int g)
{
    #pragma unroll
    for (int c = 0; c < 4; ++c) {
        f32x4 acc = {0.f, 0.f, 0.f, 0.f};
        #pragma unroll
        for (int t = 0; t < 2; ++t) {
            bf16x8 bh, bl;
            #pragma unroll
            for (int j = 0; j < 8; ++j) {
                const float wv = W[(size_t)(t * 32 + g * 8 + j) * F + c * 16 + r];
                const unsigned short hb = bf16_rne(wv);
                bh[j] = (short)hb;
                bl[j] = (short)bf16_rne(wv - bf16_f32(hb));
            }
            acc = __builtin_amdgcn_mfma_f32_16x16x32_bf16(Ah[t], bh, acc, 0, 0, 0);
            acc = __builtin_amdgcn_mfma_f32_16x16x32_bf16(Al[t], bh, acc, 0, 0, 0);
            acc = __builtin_amdgcn_mfma_f32_16x16x32_bf16(Ah[t], bl, acc, 0, 0, 0);
        }
        const float bb = bias[c * 16 + r];
        #pragma unroll
        for (int rg = 0; rg < 4; ++rg) {
            dst[(size_t)(n0 + g * 4 + rg) * F + c * 16 + r] = acc[rg] + bb;
        }
    }
}

__device__ __forceinline__ void gemm16_store_f16(
    const bf16x8 (&Ah)[2], const bf16x8 (&Al)[2],
    const float* __restrict__ W, const float* __restrict__ bias,
    _Float16* __restrict__ dst, int n0, int r, int g)
{
    #pragma unroll
    for (int c = 0; c < 4; ++c) {
        f32x4 acc = {0.f, 0.f, 0.f, 0.f};
        #pragma unroll
        for (int t = 0; t < 2; ++t) {
            bf16x8 bh, bl;
            #pragma unroll
            for (int j = 0; j < 8; ++j) {
                const float wv = W[(size_t)(t * 32 + g * 8 + j) * F + c * 16 + r];
                const unsigned short hb = bf16_rne(wv);
                bh[j] = (short)hb;
                bl[j] = (short)bf16_rne(wv - bf16_f32(hb));
            }
            acc = __builtin_amdgcn_mfma_f32_16x16x32_bf16(Ah[t], bh, acc, 0, 0, 0);
            acc = __builtin_amdgcn_mfma_f32_16x16x32_bf16(Al[t], bh, acc, 0, 0, 0);
            acc = __builtin_amdgcn_mfma_f32_16x16x32_bf16(Ah[t], bl, acc, 0, 0, 0);
        }
        const float bb = bias[c * 16 + r];
        #pragma unroll
        for (int rg = 0; rg < 4; ++rg) {
            dst[(size_t)(n0 + g * 4 + rg) * F + c * 16 + r] =
                (_Float16)(acc[rg] + bb);
        }
    }
}

// ---------------------------------------------------------------------------
// Kernel 1 (fused): node projections + edge prep.
// R14: h1 stored fp16 (6.4MB, halves edge gather bytes); record radial fp16.
// Record (16B): {src|lrow<<16, f16 r0|r1, f16 r2|r3, f32 cut}
// ---------------------------------------------------------------------------
__global__ __launch_bounds__(256) void node_prep_kernel(
    const float* __restrict__ x, const float* __restrict__ Wp,
    const float* __restrict__ bp, const float* __restrict__ W1,
    const float* __restrict__ b1,
    const int* __restrict__ ei, const float* __restrict__ pos,
    const float* __restrict__ Wr1, const float* __restrict__ br1,
    const float* __restrict__ Wr2, const float* __restrict__ br2,
    float* __restrict__ out, _Float16* __restrict__ h1,
    unsigned int* __restrict__ recs, int* __restrict__ counts)
{
    if (blockIdx.x < NODE_BLOCKS) {
        const int lane = threadIdx.x & 63;
        const int gw   = blockIdx.x * 4 + (threadIdx.x >> 6);
        if (gw >= N_NODES / 16) return;
        const int n0 = gw * 16;
        const int r = lane & 15, g = lane >> 4;

        bf16x8 Ah[2], Al[2];
        #pragma unroll
        for (int t = 0; t < 2; ++t) {
            const float* xp = x + (size_t)(n0 + r) * F + t * 32 + g * 8;
            #pragma unroll
            for (int j = 0; j < 8; ++j) {
                const float v = xp[j];
                const unsigned short hb = bf16_rne(v);
                Ah[t][j] = (short)hb;
                Al[t][j] = (short)bf16_rne(v - bf16_f32(hb));
            }
        }
        gemm16_store(Ah, Al, Wp, bp, out, n0, r, g);
        gemm16_store_f16(Ah, Al, W1, b1, h1, n0, r, g);
    } else {
        const int e = (blockIdx.x - NODE_BLOCKS) * 256 + threadIdx.x; // exact
        const int src = ei[e];
        const int tgt = ei[N_EDGES + e];
        const float dx = pos[3 * tgt + 0] - pos[3 * src + 0];
        const float dy = pos[3 * tgt + 1] - pos[3 * src + 1];
        const float dz = pos[3 * tgt + 2] - pos[3 * src + 2];
        const float d2 = dx * dx + dy * dy + dz * dz;
        if (d2 >= CUTOFF2) return;

        const float d = sqrtf(d2);
        float a0 = br2[0], a1 = br2[1], a2 = br2[2], a3 = br2[3];
        #pragma unroll
        for (int i = 0; i < 16; ++i) {
            const float t = silu_f(fmaf(d, Wr1[i], br1[i]));
            a0 = fmaf(t, Wr2[i * 4 + 0], a0);
            a1 = fmaf(t, Wr2[i * 4 + 1], a1);
            a2 = fmaf(t, Wr2[i * 4 + 2], a2);
            a3 = fmaf(t, Wr2[i * 4 + 3], a3);
        }
        const float cut = 1.0f - d2 * 0.01f;    // in (0,1] when d2 < 100

        const int b   = tgt >> 3;               // NPB = 8
        const int idx = atomicAdd(&counts[b], 1);
        if (idx < CAP) {
            uint4 rec;
            rec.x = (unsigned)src | ((unsigned)(tgt & 7) << 16);
            rec.y = (unsigned)f16_bits(silu_f(a0))
                  | ((unsigned)f16_bits(silu_f(a1)) << 16);
            rec.z = (unsigned)f16_bits(silu_f(a2))
                  | ((unsigned)f16_bits(silu_f(a3)) << 16);
            rec.w = __float_as_uint(cut);
            *(uint4*)(recs + ((size_t)b * CAP + idx) * 4) = rec;
        }
    }
}

// Per-tile in-flight state (named fields only, rule #20).
struct TileIn {
    uint4 rec;
    f16x8 hA, hB;   // h1 slices: k = g*8+j (t=0) and 32+g*8+j (t=1)
};

__device__ __forceinline__ TileIn load_tile(
    const unsigned int* __restrict__ rbase, const _Float16* __restrict__ h1,
    int base, int r, int g, int cnt)
{
    TileIn ti;
    const int er = min(base + r, cnt - 1);
    ti.rec = *(const uint4*)(rbase + (size_t)er * 4);
    const int src = (int)(ti.rec.x & 0xFFFFu);
    const _Float16* hp = h1 + (size_t)src * F + g * 8;
    ti.hA = *(const f16x8*)(hp);        // 16B
    ti.hB = *(const f16x8*)(hp + 32);   // 16B
    return ti;
}

// ---------------------------------------------------------------------------
// Kernel 2 (R14): zero-atomic edge MLP, fp16 pipeline, 2-tile ILP.
// Chain per tile: rec load + 2 (was 4) h1 loads. fp16 (10-bit mantissa)
// replaces bf16 everywhere at identical MFMA rate -> absmax should DROP.
// ---------------------------------------------------------------------------
__global__ __launch_bounds__(256, 2) void edge_main_kernel(
    const unsigned int* __restrict__ recs, const int* __restrict__ counts,
    const _Float16* __restrict__ h1, const float* __restrict__ W1,
    const float* __restrict__ W2, const float* __restrict__ b2,
    float* __restrict__ out)
{
    const int lane = threadIdx.x & 63;
    const int w    = threadIdx.x >> 6;
    const int r    = lane & 15, g = lane >> 4;

    const int bkt = blockIdx.x * 4 + w;
    if (bkt >= NBUCKET) return;
    const int cnt = min(counts[bkt], CAP);
    if (cnt == 0) return;                 // wave-uniform; rows keep node term

    // W2 B-fragments, fp16 single term (32 VGPRs). L2-hot across all waves.
    f16x8 Bh[4][2];
    #pragma unroll
    for (int c = 0; c < 4; ++c)
        #pragma unroll
        for (int t = 0; t < 2; ++t)
            #pragma unroll
            for (int jj = 0; jj < 8; ++jj)
                Bh[c][t][jj] = (_Float16)
                    W2[(size_t)(t * 32 + g * 8 + jj) * F + c * 16 + r];

    // W1 radial rows 64..67, this lane's k-slice (64 VGPRs, f32).
    float w1r[4][2][8];
    #pragma unroll
    for (int i = 0; i < 4; ++i)
        #pragma unroll
        for (int t = 0; t < 2; ++t) {
            const float4 wa = *(const float4*)&W1[(size_t)(F + i) * F + t * 32 + g * 8];
            const float4 wb = *(const float4*)&W1[(size_t)(F + i) * F + t * 32 + g * 8 + 4];
            w1r[i][t][0] = wa.x; w1r[i][t][1] = wa.y;
            w1r[i][t][2] = wa.z; w1r[i][t][3] = wa.w;
            w1r[i][t][4] = wb.x; w1r[i][t][5] = wb.y;
            w1r[i][t][6] = wb.z; w1r[i][t][7] = wb.w;
        }

    float b2c[4];
    #pragma unroll
    for (int c = 0; c < 4; ++c) b2c[c] = b2[c * 16 + r];

    const int node0 = bkt * NPB;
    const unsigned int* rbase = recs + (size_t)bkt * CAP * 4;
    const int ntiles = (cnt + 15) >> 4;

    f32x4 acc3[4] = {};   // output-stationary: aggr[4g+rg][c*16+r]

    auto compute_tile = [&](const TileIn& ti, int base) {
        const int   lrow = (int)(ti.rec.x >> 16);
        const float rr0  = f16_f32((unsigned short)(ti.rec.y & 0xFFFFu));
        const float rr1  = f16_f32((unsigned short)(ti.rec.y >> 16));
        const float rr2  = f16_f32((unsigned short)(ti.rec.z & 0xFFFFu));
        const float rr3  = f16_f32((unsigned short)(ti.rec.z >> 16));
        const float cut  = __uint_as_float(ti.rec.w);

        int   lrow_e[4]; float cut_e[4];
        #pragma unroll
        for (int rg = 0; rg < 4; ++rg) {
            const int lr = __shfl(lrow, g * 4 + rg);
            lrow_e[rg] = (base + g * 4 + rg < cnt) ? lr : -1;
            cut_e[rg]  = __shfl(cut, g * 4 + rg);
        }

        // Rank-4 radial update + silu in f32, cvt to fp16 A-fragments.
        f16x8 ah0, ah1;
        #pragma unroll
        for (int j = 0; j < 8; ++j) {
            float h0 = (float)ti.hA[j];
            h0 = fmaf(rr0, w1r[0][0][j], h0);
            h0 = fmaf(rr1, w1r[1][0][j], h0);
            h0 = fmaf(rr2, w1r[2][0][j], h0);
            h0 = fmaf(rr3, w1r[3][0][j], h0);
            ah0[j] = (_Float16)silu_f(h0);
            float h1v = (float)ti.hB[j];
            h1v = fmaf(rr0, w1r[0][1][j], h1v);
            h1v = fmaf(rr1, w1r[1][1][j], h1v);
            h1v = fmaf(rr2, w1r[2][1][j], h1v);
            h1v = fmaf(rr3, w1r[3][1][j], h1v);
            ah1[j] = (_Float16)silu_f(h1v);
        }

        // [16 x 64] @ W2 via 8 f16 MFMAs.
        f32x4 acc[4] = {};
        #pragma unroll
        for (int c = 0; c < 4; ++c) {
            acc[c] = __builtin_amdgcn_mfma_f32_16x16x32_f16(ah0, Bh[c][0], acc[c], 0, 0, 0);
            acc[c] = __builtin_amdgcn_mfma_f32_16x16x32_f16(ah1, Bh[c][1], acc[c], 0, 0, 0);
        }

        // A-fragment of P^T: A[r][k=4g+j] = (lrow_e[j] == r), exact 0/1.
        f16x4 afrag;
        afrag[0] = (lrow_e[0] == r) ? (_Float16)1.0f : (_Float16)0.0f;
        afrag[1] = (lrow_e[1] == r) ? (_Float16)1.0f : (_Float16)0.0f;
        afrag[2] = (lrow_e[2] == r) ? (_Float16)1.0f : (_Float16)0.0f;
        afrag[3] = (lrow_e[3] == r) ? (_Float16)1.0f : (_Float16)0.0f;

        // E = silu(D2+b2)*cut, hi/lo fp16 split (eff. ~21 mantissa bits);
        // zero-lane-movement B-operand feed; 2 MFMAs per c.
        #pragma unroll
        for (int c = 0; c < 4; ++c) {
            float ef[4];
            #pragma unroll
            for (int rg = 0; rg < 4; ++rg)
                ef[rg] = silu_f(acc[c][rg] + b2c[c]) * cut_e[rg];

            f16x4 beh, bel;
            #pragma unroll
            for (int rg = 0; rg < 4; ++rg) {
                const _Float16 hb = (_Float16)ef[rg];
                beh[rg] = hb;
                bel[rg] = (_Float16)(ef[rg] - (float)hb);
            }
            acc3[c] = mfma16k_f16(afrag, beh, acc3[c]);
            acc3[c] = mfma16k_f16(afrag, bel, acc3[c]);
        }
    };

    // 2-tile ILP loop: both loads issued before either compute. Phantom
    // tiles (base >= cnt) contribute exactly zero via afrag=0.
    for (int s = 0; s < ntiles; s += 2) {
        const int baseA = s << 4;
        const int baseB = (s + 1) << 4;
        const TileIn tA = load_tile(rbase, h1, baseA, r, g, cnt);
        const TileIn tB = load_tile(rbase, h1, baseB, r, g, cnt);
        compute_tile(tA, baseA);
        compute_tile(tB, baseB);
    }

    // Epilogue: wave-exclusive rows [node0, node0+8) -> plain read-add-write.
    // g >= 2 rows belong to the neighbor bucket (race if touched).
    if (g < 2) {
        #pragma unroll
        for (int rg = 0; rg < 4; ++rg) {
            float* rowp = out + (size_t)(node0 + g * 4 + rg) * F;
            #pragma unroll
            for (int c = 0; c < 4; ++c) {
                rowp[c * 16 + r] += acc3[c][rg];
            }
        }
    }
}

extern "C" void kernel_launch(void* const* d_in, const int* in_sizes, int n_in,
                              void* d_out, int out_size, void* d_ws, size_t ws_size,
                              hipStream_t stream) {
    const float* x   = (const float*)d_in[0];
    const int*   ei  = (const int*)d_in[1];
    const float* pos = (const float*)d_in[2];
    const float* Wp  = (const float*)d_in[3];
    const float* bp  = (const float*)d_in[4];
    const float* W1  = (const float*)d_in[5];
    const float* b1  = (const float*)d_in[6];
    const float* W2  = (const float*)d_in[7];
    const float* b2  = (const float*)d_in[8];
    const float* Wr1 = (const float*)d_in[9];
    const float* br1 = (const float*)d_in[10];
    const float* Wr2 = (const float*)d_in[11];
    const float* br2 = (const float*)d_in[12];
    float* out = (float*)d_out;

    // workspace: [counts 32KB][h1 fp16 6.4MB][recs 6250*96*16B = 9.6MB]
    char*         ws     = (char*)d_ws;
    int*          counts = (int*)ws;
    _Float16*     h1     = (_Float16*)(ws + 32768);
    unsigned int* recs   = (unsigned int*)(ws + 32768
                               + (size_t)N_NODES * F * sizeof(_Float16));

    hipMemsetAsync(counts, 0, NBUCKET * sizeof(int), stream);
    node_prep_kernel<<<NODE_BLOCKS + PREP_BLOCKS, 256, 0, stream>>>(
        x, Wp, bp, W1, b1, ei, pos, Wr1, br1, Wr2, br2,
        out, h1, recs, counts);
    edge_main_kernel<<<MAIN_BLOCKS, 256, 0, stream>>>(
        recs, counts, h1, W1, W2, b2, out);
}